// Round 5
// baseline (124.315 us; speedup 1.0000x reference)
//
#include <hip/hip_runtime.h>
#include <hip/hip_fp16.h>

// CPDecoding (fp32 in/out): out[n] = sum_c fz[c][n] * fy[c][n] * fx[c][n]
// fz/fy/fx: 1-D linear interp (align_corners=True) of (C=96, R=512) tables.
//
// Round-5:
//   - prep_tables (unchanged): LDS-tiled transpose (C,R) fp32 -> (R,96) fp16.
//   - cp_decode: 4 lanes/point, 16 points/wave. Row = 192 B = exactly
//     4 lanes x 3 uint4 (no padding, no dead lanes). Per-wave fixed costs
//     (coord prep, reduce, store) now amortize over 16 points instead of 4
//     (round-4 decode was VALU-issue-bound: VALUBusy 68%, HBM 2%).
//     Packed fp16 lerp + v_dot2_f32_f16 accumulate, 2-level shuffle reduce.
//   - The ~50 us delta between decode time and bench total is harness
//     restore/poison overhead (invariant across rounds 2-4); decode is the
//     only optimizable component.

namespace {
constexpr int kC = 96;
constexpr int kR = 512;
constexpr int kTab = kR * kC;  // elements per (R,C) fp16 table
}  // namespace

// ---------------- transpose/convert: (C,R) fp32 -> (R,C) fp16 ----------------
__global__ __launch_bounds__(256) void prep_tables(
    const float* __restrict__ lz, const float* __restrict__ ly,
    const float* __restrict__ lx, __half* __restrict__ out) {
  constexpr int TR = 64;  // r-tile
  constexpr int TC = 16;  // c-tile
  __shared__ float tile[TC][TR + 1];
  int b = blockIdx.x;  // 3 tables * 8 r-tiles * 6 c-tiles = 144 blocks
  int t = b / 48;
  int rem = b - t * 48;
  int rt = rem / 6;
  int ct = rem - rt * 6;
  const float* src = (t == 0) ? lz : (t == 1) ? ly : lx;
  int r0 = rt * TR, c0 = ct * TC;

  int tx = threadIdx.x & 63;   // r within tile (coalesced read)
  int ty = threadIdx.x >> 6;   // 0..3
  for (int cl = ty; cl < TC; cl += 4)
    tile[cl][tx] = src[(c0 + cl) * kR + r0 + tx];
  __syncthreads();

  int cx = threadIdx.x & 15;   // c within tile (coalesced write)
  int rl = threadIdx.x >> 4;   // 0..15
#pragma unroll
  for (int pass = 0; pass < 4; ++pass) {
    int r = rl + 16 * pass;
    out[(size_t)t * kTab + (size_t)(r0 + r) * kC + c0 + cx] =
        __float2half(tile[cx][r]);
  }
}

// ---------------- decode ----------------
__device__ __forceinline__ void prep_coord(float coord, int& i0, int& i1,
                                           float& w) {
  float pos = (coord + 1.0f) * 0.5f * (float)(kR - 1);
  float fl = floorf(pos);
  fl = fminf(fmaxf(fl, 0.0f), (float)(kR - 1));
  i0 = (int)fl;
  i1 = min(i0 + 1, kR - 1);
  w = pos - fl;
}

typedef _Float16 vh2 __attribute__((ext_vector_type(2)));
__device__ __forceinline__ float dot2acc(__half2 a, __half2 b, float c) {
#if __has_builtin(__builtin_amdgcn_fdot2)
  return __builtin_amdgcn_fdot2(*(vh2*)&a, *(vh2*)&b, c, false);
#else
  return c + __low2float(a) * __low2float(b) +
         __high2float(a) * __high2float(b);
#endif
}

__device__ __forceinline__ __half2 u2h(unsigned u) { return *(__half2*)&u; }

__global__ __launch_bounds__(256) void cp_decode(
    const float* __restrict__ pts,    // (N,3), order x,y,z
    const __half* __restrict__ tabs,  // 3 tables (R, 96) fp16
    float* __restrict__ out, int n) {
  int tid = blockIdx.x * 256 + threadIdx.x;
  int p = tid >> 2;      // 4 lanes per point
  int sl = tid & 3;      // sub-lane: comps [sl*24, sl*24+24)
  if (p >= n) return;

  float cx = pts[3 * p + 0];
  float cy = pts[3 * p + 1];
  float cz = pts[3 * p + 2];

  int iz0, iz1, iy0, iy1, ix0, ix1;
  float wz, wy, wx;
  prep_coord(cz, iz0, iz1, wz);
  prep_coord(cy, iy0, iy1, wy);
  prep_coord(cx, ix0, ix1, wx);

  const __half* tz = tabs;
  const __half* ty = tabs + kTab;
  const __half* tx = tabs + 2 * kTab;

  int sl3 = sl * 3;  // uint4 index of this lane's slice within the 12-uint4 row
  const uint4* z0 = (const uint4*)(tz + iz0 * kC) + sl3;
  const uint4* z1 = (const uint4*)(tz + iz1 * kC) + sl3;
  const uint4* y0 = (const uint4*)(ty + iy0 * kC) + sl3;
  const uint4* y1 = (const uint4*)(ty + iy1 * kC) + sl3;
  const uint4* x0 = (const uint4*)(tx + ix0 * kC) + sl3;
  const uint4* x1 = (const uint4*)(tx + ix1 * kC) + sl3;

  __half2 wz2 = __float2half2_rn(wz);
  __half2 wy2 = __float2half2_rn(wy);
  __half2 wx2 = __float2half2_rn(wx);

  float acc = 0.0f;
#pragma unroll
  for (int j = 0; j < 3; ++j) {  // 8 comps per iter, 24 comps per lane
    uint4 az0 = z0[j], az1 = z1[j];
    uint4 ay0 = y0[j], ay1 = y1[j];
    uint4 ax0 = x0[j], ax1 = x1[j];
    const unsigned* uz0 = (const unsigned*)&az0;
    const unsigned* uz1 = (const unsigned*)&az1;
    const unsigned* uy0 = (const unsigned*)&ay0;
    const unsigned* uy1 = (const unsigned*)&ay1;
    const unsigned* ux0 = (const unsigned*)&ax0;
    const unsigned* ux1 = (const unsigned*)&ax1;
#pragma unroll
    for (int k = 0; k < 4; ++k) {
      __half2 hz0 = u2h(uz0[k]), hz1 = u2h(uz1[k]);
      __half2 hy0 = u2h(uy0[k]), hy1 = u2h(uy1[k]);
      __half2 hx0 = u2h(ux0[k]), hx1 = u2h(ux1[k]);
      __half2 fz = __hfma2(wz2, __hsub2(hz1, hz0), hz0);
      __half2 fy = __hfma2(wy2, __hsub2(hy1, hy0), hy0);
      __half2 fx = __hfma2(wx2, __hsub2(hx1, hx0), hx0);
      acc = dot2acc(__hmul2(fz, fy), fx, acc);
    }
  }

  // reduce over the 4-lane group
  acc += __shfl_xor(acc, 2);
  acc += __shfl_xor(acc, 1);

  if (sl == 0) out[p] = acc;
}

// Fallback (ws too small): gather directly from (C,R) fp32 layout.
__global__ __launch_bounds__(256) void cp_decode_f32_direct(
    const float* __restrict__ pts, const float* __restrict__ lz,
    const float* __restrict__ ly, const float* __restrict__ lx,
    float* __restrict__ out, int n) {
  int i = blockIdx.x * blockDim.x + threadIdx.x;
  if (i >= n) return;
  float cx = pts[3 * i + 0], cy = pts[3 * i + 1], cz = pts[3 * i + 2];
  int iz0, iz1, iy0, iy1, ix0, ix1;
  float wz, wy, wx;
  prep_coord(cz, iz0, iz1, wz);
  prep_coord(cy, iy0, iy1, wy);
  prep_coord(cx, ix0, ix1, wx);
  float acc = 0.0f;
  for (int c = 0; c < kC; ++c) {
    float fz = fmaf(wz, lz[c * kR + iz1] - lz[c * kR + iz0], lz[c * kR + iz0]);
    float fy = fmaf(wy, ly[c * kR + iy1] - ly[c * kR + iy0], ly[c * kR + iy0]);
    float fx = fmaf(wx, lx[c * kR + ix1] - lx[c * kR + ix0], lx[c * kR + ix0]);
    acc = fmaf(fz * fy, fx, acc);
  }
  out[i] = acc;
}

extern "C" void kernel_launch(void* const* d_in, const int* in_sizes, int n_in,
                              void* d_out, int out_size, void* d_ws, size_t ws_size,
                              hipStream_t stream) {
  const float* pts = (const float*)d_in[0];  // in_tensor (N,3)
  const float* lz  = (const float*)d_in[1];  // line_z (C,R)
  const float* ly  = (const float*)d_in[2];  // line_y
  const float* lx  = (const float*)d_in[3];  // line_x
  float* outp = (float*)d_out;

  int n = out_size;  // 786432 points
  size_t need = (size_t)3 * kTab * sizeof(__half);  // 288 KB

  if (ws_size >= need) {
    __half* tabs = (__half*)d_ws;
    prep_tables<<<144, 256, 0, stream>>>(lz, ly, lx, tabs);
    // 4 lanes/point, 256 threads/block -> 64 points/block
    long long threads = (long long)n * 4;
    int blocks = (int)((threads + 255) / 256);
    cp_decode<<<blocks, 256, 0, stream>>>(pts, tabs, outp, n);
  } else {
    cp_decode_f32_direct<<<(n + 255) / 256, 256, 0, stream>>>(pts, lz, ly, lx,
                                                              outp, n);
  }
}

// Round 6
// 104.957 us; speedup vs baseline: 1.1844x; 1.1844x over previous
//
#include <hip/hip_runtime.h>
#include <hip/hip_fp16.h>

// CPDecoding (fp32 in/out): out[n] = sum_c fz[c][n] * fy[c][n] * fx[c][n]
// fz/fy/fx: 1-D linear interp (align_corners=True) of (C=96, R=512) tables.
//
// Round-6: balance the two empirically-fitted costs
//   (a) TA tag cost ~1 cyc per distinct-cache-line per vmem instr per CU
//       R4 (16 ln/pt): 24 tags/pt -> 31 us;  R5 (4 ln/pt): 54 tags/pt -> 69 us
//   (b) VALU issue: R4 20.5 winst/pt -> 38 us; R5 6.6/pt -> 13 us
//   => 8 lanes/point with full-row-contiguous loads hits the tag FLOOR
//      (6 rows x 3 lines = 18 tags/pt, rows are 192 B and 64-B aligned) at
//      ~12.6 winst/pt: both pipes ~23 us, overlap -> ~30 us decode.
//   - Row load = dwordx4 @ sl*16 (bytes 0..127) + dwordx2 @ 128+sl*8.
//   - Tables padded to 513 rows (row 512 = copy of row 511, written from the
//     original source so there's no inter-block race) => i1 = i0+1 always,
//     no clamp, no boundary branch.

namespace {
constexpr int kC = 96;
constexpr int kR = 512;
constexpr int kRPad = 513;
constexpr int kTab = kRPad * kC;  // elements per (R+1,C) fp16 table
}  // namespace

// -------- transpose/convert: (C,R) fp32 -> (R+1, C) fp16, 64-B aligned rows --
__global__ __launch_bounds__(256) void prep_tables(
    const float* __restrict__ lz, const float* __restrict__ ly,
    const float* __restrict__ lx, __half* __restrict__ out) {
  int b = blockIdx.x;
  if (b >= 144) {
    // pad block: row 512 <- source row 511 for all 3 tables (288 values)
    for (int idx = threadIdx.x; idx < 3 * kC; idx += 256) {
      int t = idx / kC;
      int c = idx - t * kC;
      const float* src = (t == 0) ? lz : (t == 1) ? ly : lx;
      out[(size_t)t * kTab + (size_t)512 * kC + c] =
          __float2half(src[c * kR + 511]);
    }
    return;
  }
  constexpr int TR = 64;  // r-tile
  constexpr int TC = 16;  // c-tile
  __shared__ float tile[TC][TR + 1];
  int t = b / 48;  // 3 tables * 8 r-tiles * 6 c-tiles
  int rem = b - t * 48;
  int rt = rem / 6;
  int ct = rem - rt * 6;
  const float* src = (t == 0) ? lz : (t == 1) ? ly : lx;
  int r0 = rt * TR, c0 = ct * TC;

  int tx = threadIdx.x & 63;  // r within tile (coalesced read)
  int ty = threadIdx.x >> 6;  // 0..3
  for (int cl = ty; cl < TC; cl += 4)
    tile[cl][tx] = src[(c0 + cl) * kR + r0 + tx];
  __syncthreads();

  int cx = threadIdx.x & 15;  // c within tile (coalesced write)
  int rl = threadIdx.x >> 4;  // 0..15
#pragma unroll
  for (int pass = 0; pass < 4; ++pass) {
    int r = rl + 16 * pass;
    out[(size_t)t * kTab + (size_t)(r0 + r) * kC + c0 + cx] =
        __float2half(tile[cx][r]);
  }
}

// ---------------- decode ----------------
typedef float vf3 __attribute__((ext_vector_type(3)));
typedef _Float16 vh2 __attribute__((ext_vector_type(2)));

__device__ __forceinline__ float dot2acc(__half2 a, __half2 b, float c) {
#if __has_builtin(__builtin_amdgcn_fdot2)
  return __builtin_amdgcn_fdot2(*(vh2*)&a, *(vh2*)&b, c, false);
#else
  return c + __low2float(a) * __low2float(b) +
         __high2float(a) * __high2float(b);
#endif
}

__device__ __forceinline__ __half2 u2h(unsigned u) { return *(__half2*)&u; }

__device__ __forceinline__ void prep_coord(float coord, int& i0, float& w) {
  float pos = (coord + 1.0f) * 0.5f * (float)(kR - 1);
  float fl = floorf(pos);
  fl = fminf(fmaxf(fl, 0.0f), (float)(kR - 1));
  i0 = (int)fl;
  w = pos - fl;  // i1 = i0 + 1 always valid (padded row 512)
}

__global__ __launch_bounds__(256) void cp_decode(
    const float* __restrict__ pts,    // (N,3), order x,y,z
    const __half* __restrict__ tabs,  // 3 tables (513, 96) fp16
    float* __restrict__ out, int n) {
  int tid = blockIdx.x * 256 + threadIdx.x;
  int p = tid >> 3;  // 8 lanes per point
  int sl = tid & 7;  // sub-lane
  if (p >= n) return;

  vf3 crd = *(const vf3*)(pts + 3 * (size_t)p);  // dwordx3
  float cx = crd.x, cy = crd.y, cz = crd.z;

  int iz0, iy0, ix0;
  float wz, wy, wx;
  prep_coord(cz, iz0, wz);
  prep_coord(cy, iy0, wy);
  prep_coord(cx, ix0, wx);

  const __half* rz = tabs + (size_t)iz0 * kC;
  const __half* ry = tabs + kTab + (size_t)iy0 * kC;
  const __half* rx = tabs + 2 * (size_t)kTab + (size_t)ix0 * kC;

  // Row pair r, r+1 are contiguous 192-B rows. Lane covers:
  //   A: comps [sl*8,  sl*8+8)  via dwordx4 at byte sl*16
  //   B: comps [64+sl*4, 64+sl*4+4) via dwordx2 at byte 128+sl*8
  const uint4* z0a = (const uint4*)rz + sl;
  const uint4* y0a = (const uint4*)ry + sl;
  const uint4* x0a = (const uint4*)rx + sl;
  const uint2* z0b = (const uint2*)(rz + 64) + sl;
  const uint2* y0b = (const uint2*)(ry + 64) + sl;
  const uint2* x0b = (const uint2*)(rx + 64) + sl;
  constexpr int kRowU4 = kC / 8;  // 12 uint4 per row
  constexpr int kRowU2 = kC / 4;  // 24 uint2 per row

  uint4 az0 = z0a[0], az1 = z0a[kRowU4];
  uint4 ay0 = y0a[0], ay1 = y0a[kRowU4];
  uint4 ax0 = x0a[0], ax1 = x0a[kRowU4];
  uint2 bz0 = z0b[0], bz1 = z0b[kRowU2];
  uint2 by0 = y0b[0], by1 = y0b[kRowU2];
  uint2 bx0 = x0b[0], bx1 = x0b[kRowU2];

  __half2 wz2 = __float2half2_rn(wz);
  __half2 wy2 = __float2half2_rn(wy);
  __half2 wx2 = __float2half2_rn(wx);

  float acc = 0.0f;
  {
    const unsigned* uz0 = (const unsigned*)&az0;
    const unsigned* uz1 = (const unsigned*)&az1;
    const unsigned* uy0 = (const unsigned*)&ay0;
    const unsigned* uy1 = (const unsigned*)&ay1;
    const unsigned* ux0 = (const unsigned*)&ax0;
    const unsigned* ux1 = (const unsigned*)&ax1;
#pragma unroll
    for (int k = 0; k < 4; ++k) {
      __half2 hz0 = u2h(uz0[k]), hz1 = u2h(uz1[k]);
      __half2 hy0 = u2h(uy0[k]), hy1 = u2h(uy1[k]);
      __half2 hx0 = u2h(ux0[k]), hx1 = u2h(ux1[k]);
      __half2 fz = __hfma2(wz2, __hsub2(hz1, hz0), hz0);
      __half2 fy = __hfma2(wy2, __hsub2(hy1, hy0), hy0);
      __half2 fx = __hfma2(wx2, __hsub2(hx1, hx0), hx0);
      acc = dot2acc(__hmul2(fz, fy), fx, acc);
    }
  }
  {
    const unsigned* uz0 = (const unsigned*)&bz0;
    const unsigned* uz1 = (const unsigned*)&bz1;
    const unsigned* uy0 = (const unsigned*)&by0;
    const unsigned* uy1 = (const unsigned*)&by1;
    const unsigned* ux0 = (const unsigned*)&bx0;
    const unsigned* ux1 = (const unsigned*)&bx1;
#pragma unroll
    for (int k = 0; k < 2; ++k) {
      __half2 hz0 = u2h(uz0[k]), hz1 = u2h(uz1[k]);
      __half2 hy0 = u2h(uy0[k]), hy1 = u2h(uy1[k]);
      __half2 hx0 = u2h(ux0[k]), hx1 = u2h(ux1[k]);
      __half2 fz = __hfma2(wz2, __hsub2(hz1, hz0), hz0);
      __half2 fy = __hfma2(wy2, __hsub2(hy1, hy0), hy0);
      __half2 fx = __hfma2(wx2, __hsub2(hx1, hx0), hx0);
      acc = dot2acc(__hmul2(fz, fy), fx, acc);
    }
  }

  // reduce over the 8-lane group
  acc += __shfl_xor(acc, 4);
  acc += __shfl_xor(acc, 2);
  acc += __shfl_xor(acc, 1);

  if (sl == 0) out[p] = acc;
}

// Fallback (ws too small): gather directly from (C,R) fp32 layout.
__global__ __launch_bounds__(256) void cp_decode_f32_direct(
    const float* __restrict__ pts, const float* __restrict__ lz,
    const float* __restrict__ ly, const float* __restrict__ lx,
    float* __restrict__ out, int n) {
  int i = blockIdx.x * blockDim.x + threadIdx.x;
  if (i >= n) return;
  float cx = pts[3 * i + 0], cy = pts[3 * i + 1], cz = pts[3 * i + 2];
  auto pc = [](float coord, int& i0, int& i1, float& w) {
    float pos = (coord + 1.0f) * 0.5f * (float)(kR - 1);
    float fl = floorf(pos);
    fl = fminf(fmaxf(fl, 0.0f), (float)(kR - 1));
    i0 = (int)fl;
    i1 = min(i0 + 1, kR - 1);
    w = pos - fl;
  };
  int iz0, iz1, iy0, iy1, ix0, ix1;
  float wz, wy, wx;
  pc(cz, iz0, iz1, wz);
  pc(cy, iy0, iy1, wy);
  pc(cx, ix0, ix1, wx);
  float acc = 0.0f;
  for (int c = 0; c < kC; ++c) {
    float fz = fmaf(wz, lz[c * kR + iz1] - lz[c * kR + iz0], lz[c * kR + iz0]);
    float fy = fmaf(wy, ly[c * kR + iy1] - ly[c * kR + iy0], ly[c * kR + iy0]);
    float fx = fmaf(wx, lx[c * kR + ix1] - lx[c * kR + ix0], lx[c * kR + ix0]);
    acc = fmaf(fz * fy, fx, acc);
  }
  out[i] = acc;
}

extern "C" void kernel_launch(void* const* d_in, const int* in_sizes, int n_in,
                              void* d_out, int out_size, void* d_ws, size_t ws_size,
                              hipStream_t stream) {
  const float* pts = (const float*)d_in[0];  // in_tensor (N,3)
  const float* lz  = (const float*)d_in[1];  // line_z (C,R)
  const float* ly  = (const float*)d_in[2];  // line_y
  const float* lx  = (const float*)d_in[3];  // line_x
  float* outp = (float*)d_out;

  int n = out_size;  // 786432 points
  size_t need = (size_t)3 * kTab * sizeof(__half);  // ~289 KB

  if (ws_size >= need) {
    __half* tabs = (__half*)d_ws;
    prep_tables<<<145, 256, 0, stream>>>(lz, ly, lx, tabs);
    // 8 lanes/point, 256 threads/block -> 32 points/block
    long long threads = (long long)n * 8;
    int blocks = (int)((threads + 255) / 256);
    cp_decode<<<blocks, 256, 0, stream>>>(pts, tabs, outp, n);
  } else {
    cp_decode_f32_direct<<<(n + 255) / 256, 256, 0, stream>>>(pts, lz, ly, lx,
                                                              outp, n);
  }
}

// Round 7
// 94.577 us; speedup vs baseline: 1.3144x; 1.1098x over previous
//
#include <hip/hip_runtime.h>
#include <hip/hip_fp16.h>

// CPDecoding (fp32 in/out): out[n] = sum_c fz[c][n] * fy[c][n] * fx[c][n]
// fz/fy/fx: 1-D linear interp (align_corners=True) of (C=96, R=512) tables.
//
// Round-7: kill the L1 misses entirely.
//   Fitted model from R4-R6: TCP cost ~2 cyc per L1-miss line, ~1 per hit;
//   18 miss-lines/pt -> 46 us floor for any global-gather structure.
//   KEY FACT: coords are uniform[0,1) -> pos in [255.5, 511) -> table rows
//   0..254 are NEVER read. Hot set = rows 255..512 x 3 tables ~ 149 KB,
//   which FITS IN LDS (160 KiB).
//   - Persistent blocks: 256 blocks x 1024 threads (1 block/CU, 16 waves),
//     each stages rows 255..512 of all 3 fp16 tables into dynamic LDS
//     (row stride padded 192->208 B to spread bank aliasing), then
//     grid-strides over points. Table reads: ds_read_b128/b64 only.
//   - Safety: any row < 255 (impossible for this input dist) falls back to
//     the global tables in ws; uniformly-false branch costs ~nothing.
//   - Fallback if >64KB dynamic LDS is rejected: stage z-table only (53 KB).
//   Predicted decode ~24-30 us (LDS pipe ~19 us + VALU ~20 us overlapped).

namespace {
constexpr int kC = 96;
constexpr int kR = 512;
constexpr int kRPad = 513;
constexpr int kTab = kRPad * kC;   // elements per (R+1,C) fp16 table
constexpr int kBase = 255;         // first LDS-staged row
constexpr int kRowsLds = kRPad - kBase;  // 258 rows
constexpr int kLdsRowH = 104;      // padded LDS row stride in halves (208 B)
constexpr int kTabLdsB = kRowsLds * kLdsRowH * 2;  // 53664 B per table
}  // namespace

// -------- transpose/convert: (C,R) fp32 -> (R+1, C) fp16 --------
__global__ __launch_bounds__(256) void prep_tables(
    const float* __restrict__ lz, const float* __restrict__ ly,
    const float* __restrict__ lx, __half* __restrict__ out) {
  int b = blockIdx.x;
  if (b >= 144) {
    for (int idx = threadIdx.x; idx < 3 * kC; idx += 256) {
      int t = idx / kC;
      int c = idx - t * kC;
      const float* src = (t == 0) ? lz : (t == 1) ? ly : lx;
      out[(size_t)t * kTab + (size_t)512 * kC + c] =
          __float2half(src[c * kR + 511]);
    }
    return;
  }
  constexpr int TR = 64;
  constexpr int TC = 16;
  __shared__ float tile[TC][TR + 1];
  int t = b / 48;
  int rem = b - t * 48;
  int rt = rem / 6;
  int ct = rem - rt * 6;
  const float* src = (t == 0) ? lz : (t == 1) ? ly : lx;
  int r0 = rt * TR, c0 = ct * TC;

  int tx = threadIdx.x & 63;
  int ty = threadIdx.x >> 6;
  for (int cl = ty; cl < TC; cl += 4)
    tile[cl][tx] = src[(c0 + cl) * kR + r0 + tx];
  __syncthreads();

  int cx = threadIdx.x & 15;
  int rl = threadIdx.x >> 4;
#pragma unroll
  for (int pass = 0; pass < 4; ++pass) {
    int r = rl + 16 * pass;
    out[(size_t)t * kTab + (size_t)(r0 + r) * kC + c0 + cx] =
        __float2half(tile[cx][r]);
  }
}

// ---------------- decode ----------------
typedef float vf3 __attribute__((ext_vector_type(3)));
typedef _Float16 vh2 __attribute__((ext_vector_type(2)));

__device__ __forceinline__ float dot2acc(__half2 a, __half2 b, float c) {
#if __has_builtin(__builtin_amdgcn_fdot2)
  return __builtin_amdgcn_fdot2(*(vh2*)&a, *(vh2*)&b, c, false);
#else
  return c + __low2float(a) * __low2float(b) +
         __high2float(a) * __high2float(b);
#endif
}

__device__ __forceinline__ __half2 u2h(unsigned u) { return *(__half2*)&u; }

__device__ __forceinline__ void prep_coord(float coord, int& i0, float& w) {
  float pos = (coord + 1.0f) * 0.5f * (float)(kR - 1);
  float fl = floorf(pos);
  fl = fminf(fmaxf(fl, 0.0f), (float)(kR - 1));
  i0 = (int)fl;
  w = pos - fl;  // i1 = i0 + 1 always valid (padded row 512)
}

struct RowPair { uint4 a0, a1; uint2 b0, b1; };
struct Frag { __half2 v[6]; };  // this lane's 12 lerped comps

// r0/r1 may point into LDS or global; addrspace is inferred per call site.
__device__ __forceinline__ RowPair load_pair(const __half* r0,
                                             const __half* r1, int sl) {
  RowPair p;
  p.a0 = *((const uint4*)r0 + sl);          // comps [sl*8, sl*8+8)
  p.a1 = *((const uint4*)r1 + sl);
  p.b0 = *((const uint2*)(r0 + 64) + sl);   // comps [64+sl*4, 64+sl*4+4)
  p.b1 = *((const uint2*)(r1 + 64) + sl);
  return p;
}

__device__ __forceinline__ Frag lerp_pair(const RowPair& p, __half2 w) {
  Frag f;
  const unsigned* u0 = (const unsigned*)&p.a0;
  const unsigned* u1 = (const unsigned*)&p.a1;
#pragma unroll
  for (int k = 0; k < 4; ++k)
    f.v[k] = __hfma2(w, __hsub2(u2h(u1[k]), u2h(u0[k])), u2h(u0[k]));
  const unsigned* w0 = (const unsigned*)&p.b0;
  const unsigned* w1 = (const unsigned*)&p.b1;
#pragma unroll
  for (int k = 0; k < 2; ++k)
    f.v[4 + k] = __hfma2(w, __hsub2(u2h(w1[k]), u2h(w0[k])), u2h(w0[k]));
  return f;
}

__global__ __launch_bounds__(1024) void cp_decode_lds(
    const float* __restrict__ pts,    // (N,3), order x,y,z
    const __half* __restrict__ tabs,  // 3 tables (513, 96) fp16 in ws
    float* __restrict__ out, int n, int nLdsTabs) {
  extern __shared__ __align__(16) unsigned char smem[];

  // ---- stage rows [kBase, 513) of nLdsTabs tables into padded LDS ----
  for (int t = 0; t < nLdsTabs; ++t) {
    const uint4* g = (const uint4*)(tabs + (size_t)t * kTab + kBase * kC);
    uint4* s = (uint4*)(smem + (size_t)t * kTabLdsB);
    for (int i = threadIdx.x; i < kRowsLds * 12; i += blockDim.x) {
      int r = i / 12;
      int c = i - r * 12;
      s[r * 13 + c] = g[i];  // src rows contiguous (12 u4), dst stride 13 u4
    }
  }
  __syncthreads();

  int sl = threadIdx.x & 7;           // 8 lanes per point
  int lanePt = threadIdx.x >> 3;
  int ptsPerBlk = blockDim.x >> 3;    // 128
  int stride = gridDim.x * ptsPerBlk;

  for (int p = blockIdx.x * ptsPerBlk + lanePt; p < n; p += stride) {
    vf3 crd = *(const vf3*)(pts + 3 * (size_t)p);
    int i0[3];
    float w[3];
    prep_coord(crd.z, i0[0], w[0]);  // table 0 = z
    prep_coord(crd.y, i0[1], w[1]);  // table 1 = y
    prep_coord(crd.x, i0[2], w[2]);  // table 2 = x

    Frag f[3];
#pragma unroll
    for (int t = 0; t < 3; ++t) {
      RowPair rp;
      int r = i0[t];
      if (t < nLdsTabs && r >= kBase) {
        const __half* s0 = (const __half*)(smem + (size_t)t * kTabLdsB) +
                           (size_t)(r - kBase) * kLdsRowH;
        rp = load_pair(s0, s0 + kLdsRowH, sl);
      } else {  // never taken for uniform[0,1) coords; correctness safety
        const __half* g0 = tabs + (size_t)t * kTab + (size_t)r * kC;
        rp = load_pair(g0, g0 + kC, sl);
      }
      f[t] = lerp_pair(rp, __float2half2_rn(w[t]));
    }

    float acc = 0.0f;
#pragma unroll
    for (int k = 0; k < 6; ++k)
      acc = dot2acc(__hmul2(f[0].v[k], f[1].v[k]), f[2].v[k], acc);

    acc += __shfl_xor(acc, 4);
    acc += __shfl_xor(acc, 2);
    acc += __shfl_xor(acc, 1);
    if (sl == 0) out[p] = acc;
  }
}

// Fallback (ws too small): gather directly from (C,R) fp32 layout.
__global__ __launch_bounds__(256) void cp_decode_f32_direct(
    const float* __restrict__ pts, const float* __restrict__ lz,
    const float* __restrict__ ly, const float* __restrict__ lx,
    float* __restrict__ out, int n) {
  int i = blockIdx.x * blockDim.x + threadIdx.x;
  if (i >= n) return;
  float cx = pts[3 * i + 0], cy = pts[3 * i + 1], cz = pts[3 * i + 2];
  auto pc = [](float coord, int& i0, int& i1, float& w) {
    float pos = (coord + 1.0f) * 0.5f * (float)(kR - 1);
    float fl = floorf(pos);
    fl = fminf(fmaxf(fl, 0.0f), (float)(kR - 1));
    i0 = (int)fl;
    i1 = min(i0 + 1, kR - 1);
    w = pos - fl;
  };
  int iz0, iz1, iy0, iy1, ix0, ix1;
  float wz, wy, wx;
  pc(cz, iz0, iz1, wz);
  pc(cy, iy0, iy1, wy);
  pc(cx, ix0, ix1, wx);
  float acc = 0.0f;
  for (int c = 0; c < kC; ++c) {
    float fz = fmaf(wz, lz[c * kR + iz1] - lz[c * kR + iz0], lz[c * kR + iz0]);
    float fy = fmaf(wy, ly[c * kR + iy1] - ly[c * kR + iy0], ly[c * kR + iy0]);
    float fx = fmaf(wx, lx[c * kR + ix1] - lx[c * kR + ix0], lx[c * kR + ix0]);
    acc = fmaf(fz * fy, fx, acc);
  }
  out[i] = acc;
}

extern "C" void kernel_launch(void* const* d_in, const int* in_sizes, int n_in,
                              void* d_out, int out_size, void* d_ws, size_t ws_size,
                              hipStream_t stream) {
  const float* pts = (const float*)d_in[0];  // in_tensor (N,3)
  const float* lz  = (const float*)d_in[1];  // line_z (C,R)
  const float* ly  = (const float*)d_in[2];  // line_y
  const float* lx  = (const float*)d_in[3];  // line_x
  float* outp = (float*)d_out;

  int n = out_size;  // 786432 points
  size_t need = (size_t)3 * kTab * sizeof(__half);  // ~295 KB

  if (ws_size >= need) {
    __half* tabs = (__half*)d_ws;
    prep_tables<<<145, 256, 0, stream>>>(lz, ly, lx, tabs);

    int nLdsTabs, grid, dynB;
    hipError_t e = hipFuncSetAttribute(
        (const void*)cp_decode_lds,
        hipFuncAttributeMaxDynamicSharedMemorySize, 3 * kTabLdsB);
    if (e == hipSuccess) {
      nLdsTabs = 3;            // all 3 tables in LDS: 160992 B
      grid = 256;              // 1 block/CU, persistent
      dynB = 3 * kTabLdsB;
    } else {
      nLdsTabs = 1;            // z-table only: 53664 B (< 64 KB default)
      grid = 512;              // 2 blocks/CU
      dynB = kTabLdsB;
    }
    cp_decode_lds<<<grid, 1024, dynB, stream>>>(pts, tabs, outp, n, nLdsTabs);
  } else {
    cp_decode_f32_direct<<<(n + 255) / 256, 256, 0, stream>>>(pts, lz, ly, lx,
                                                              outp, n);
  }
}